// Round 13
// baseline (594.638 us; speedup 1.0000x reference)
//
#include <hip/hip_runtime.h>

#define N_PTS 200000
#define KC    512
#define DIM   128
#define NITER 3
#define EPS   1e-10
#define BETA  1e-3
#define PWIN  0.35f     // bf16-pruner window: f64 arg>=-32 band (0.032) + >10sigma bf16 slack
#define ACUT  -32.0     // weights below e^-32 shift centers ~1e-12 -> negligible
#define LCAND 16
#define NSUB  8         // sub-buckets per center (atomic line-contention fix, R11)
#define SUBCAP 512      // per-sub bucket capacity (total 4096/center)
#define CSTRIDE 16      // cursor padded to 64 B: one cache line per sub-cursor
#define NTILE (N_PTS / 32)   // 6250 point-tiles

typedef __attribute__((ext_vector_type(8)))  short short8;   // 8 bf16 (4 VGPR) MFMA A/B frag
typedef __attribute__((ext_vector_type(16))) float f32x16;   // 32x32 MFMA accumulator

__device__ inline unsigned short f2bf(float f) {             // f32 -> bf16 RNE
    unsigned u = __float_as_uint(f);
    unsigned r = u + 0x7FFFu + ((u >> 16) & 1u);
    return (unsigned short)(r >> 16);
}

// A/B fragment layout for mfma_f32_32x32x16_bf16: entity row/col = lane&31,
// k = (lane>>5)*8 + i, i=0..7. Packed flat: [(tile*8 + kb)*64 + lane] as short8.

// ---------------- k_packx: X -> bf16 A-fragments (once; x is iteration-invariant) ----------------
__global__ void k_packx(const float* __restrict__ x, short8* __restrict__ Xf) {
    int pt = blockIdx.x;                       // 6250 point-tiles of 32
    int tid = threadIdx.x;                     // 256
    int lane = tid & 63, g = tid >> 6;
    int row = pt * 32 + (lane & 31);
    int koff = (lane >> 5) * 8;
    #pragma unroll
    for (int kk = 0; kk < 2; ++kk) {
        int kb = g * 2 + kk;
        short8 v;
        #pragma unroll
        for (int i = 0; i < 8; ++i)
            ((unsigned short*)&v)[i] = f2bf(x[(size_t)row * DIM + kb * 16 + koff + i]);
        Xf[((size_t)pt * 8 + kb) * 64 + lane] = v;
    }
}

// ---------------- k_init: Cf64, C-fragments, csq, zero num/den/cursors ----------------
__global__ void k_init(const float* __restrict__ cin, double* __restrict__ Cf64,
                       unsigned short* __restrict__ Cfrag, double* __restrict__ csqd,
                       float* __restrict__ csqf, double* __restrict__ num,
                       double* __restrict__ den, unsigned* __restrict__ cursor) {
    int k = blockIdx.x, d = threadIdx.x;       // 512 blocks x 128 threads
    float v = cin[k * DIM + d];
    double c = (double)v;
    Cf64[(size_t)k * DIM + d] = c;
    num[(size_t)k * DIM + d] = 0.0;
    if (d < NSUB) cursor[((size_t)k * NSUB + d) * CSTRIDE] = 0u;
    int ct = k >> 5, kb = d >> 4, j = d & 15;
    int lane = (k & 31) + 32 * (j >> 3);
    Cfrag[(((size_t)ct * 8 + kb) * 64 + lane) * 8 + (j & 7)] = f2bf(v);
    double p = c * c;
    #pragma unroll
    for (int m = 1; m < 64; m <<= 1) p += __shfl_xor(p, m);
    __shared__ double ps[2];
    if ((d & 63) == 0) ps[d >> 6] = p;
    __syncthreads();
    if (d == 0) {
        double s = ps[0] + ps[1];
        csqd[k] = s; csqf[k] = (float)s;
        den[k] = 0.0;
    }
}

// ---------------- k_dense: barrier-free wave-per-tile; 2-pass MFMA prune + f64 refine ----------------
// 256 threads = 4 INDEPENDENT waves; each wave owns one 32-point tile x all 512 centers.
// launch_bounds(256,2): VGPR cap 256 so a[8]/acc/runmin stay LIVE (R12's 48-VGPR
// rematerialization serialized ~500 memory round-trips per wave).
// Both ct-loops fully unrolled -> compiler hoists loads, pipelines under MFMA.
__launch_bounds__(256, 2)
__global__ void k_dense(const float* __restrict__ x, const short8* __restrict__ Xf,
                        const short8* __restrict__ Cfrag, const float* __restrict__ csqf,
                        const double* __restrict__ Cf64, const double* __restrict__ csqd,
                        unsigned* __restrict__ cursor,
                        unsigned* __restrict__ entries_n, double* __restrict__ entries_w) {
    __shared__ int            ccnt[4][32];
    __shared__ unsigned short clist[4][32][LCAND];

    const int tid = threadIdx.x;
    const int wv = tid >> 6, lane = tid & 63;
    const int tile = blockIdx.x * 4 + wv;
    if (tile >= NTILE) return;                 // no barriers -> safe early exit
    const int sub = tile & (NSUB - 1);
    const int h = lane >> 5;

    // A-fragments: this tile's 32 points, full K=128 (32 VGPR, kept live)
    short8 a[8];
    #pragma unroll
    for (int kb = 0; kb < 8; ++kb)
        a[kb] = Xf[((size_t)tile * 8 + kb) * 64 + lane];

    // ---- pass 1: running per-row min over all 16 col-tiles (fully unrolled) ----
    float runmin[16];
    #pragma unroll
    for (int r = 0; r < 16; ++r) runmin[r] = 1e30f;
    #pragma unroll
    for (int ct = 0; ct < 16; ++ct) {
        f32x16 acc;
        #pragma unroll
        for (int r = 0; r < 16; ++r) acc[r] = 0.0f;
        #pragma unroll
        for (int kb = 0; kb < 8; ++kb) {
            short8 b = Cfrag[((size_t)ct * 8 + kb) * 64 + lane];
            acc = __builtin_amdgcn_mfma_f32_32x32x16_bf16(a[kb], b, acc, 0, 0, 0);
        }
        float cq = csqf[ct * 32 + (lane & 31)];
        #pragma unroll
        for (int r = 0; r < 16; ++r) runmin[r] = fminf(runmin[r], cq - 2.0f * acc[r]);
    }
    // cross-lane min over the 32 cols of this half; rows are half-exclusive, so
    // after the butterfly EVERY lane holds the full 512-center min for its rows.
    float thr[16];
    #pragma unroll
    for (int r = 0; r < 16; ++r) {
        float m = runmin[r];
        #pragma unroll
        for (int s = 16; s >= 1; s >>= 1) m = fminf(m, __shfl_xor(m, s));
        thr[r] = m + PWIN;                     // register threshold; no LDS round-trip
    }
    if (lane < 32) ccnt[wv][lane] = 0;

    // ---- pass 2: recompute MFMA (bit-identical), collect vs FINAL min (unrolled) ----
    #pragma unroll
    for (int ct = 0; ct < 16; ++ct) {
        f32x16 acc;
        #pragma unroll
        for (int r = 0; r < 16; ++r) acc[r] = 0.0f;
        #pragma unroll
        for (int kb = 0; kb < 8; ++kb) {
            short8 b = Cfrag[((size_t)ct * 8 + kb) * 64 + lane];
            acc = __builtin_amdgcn_mfma_f32_32x32x16_bf16(a[kb], b, acc, 0, 0, 0);
        }
        float cq = csqf[ct * 32 + (lane & 31)];
        #pragma unroll
        for (int r = 0; r < 16; ++r) {
            float ddv = cq - 2.0f * acc[r];
            if (ddv < thr[r]) {
                int row = (r & 3) + 8 * (r >> 2) + 4 * h;
                int idx = atomicAdd(&ccnt[wv][row], 1);
                if (idx < LCAND)
                    clist[wv][row][idx] = (unsigned short)(ct * 32 + (lane & 31));
            }
        }
    }

    // ---- cnt==1 fast path: 32 PARALLEL appends (lanes 0..31, one point each) ----
    // Sole candidate IS the argmin; all others sit >= ~e^-250 below in f64
    // => weight is bit-exactly 1.0. No dot, no softmax, no x read.
    if (lane < 32 && ccnt[wv][lane] == 1) {
        int k = clist[wv][lane][0];
        size_t base = (size_t)k * NSUB + sub;
        unsigned pos = atomicAdd(&cursor[base * CSTRIDE], 1u);
        if (pos < SUBCAP) {
            entries_n[base * SUBCAP + pos] = (unsigned)(tile * 32 + lane);
            entries_w[base * SUBCAP + pos] = 1.0;
        }
    }

    // ---- refine: wave-sequential over this tile's cnt>=2 points ----
    unsigned long long rmask = __ballot(lane < 32 && ccnt[wv][lane] > 1);
    while (rmask) {
        int p = __ffsll(rmask) - 1;
        rmask &= rmask - 1;
        int n = tile * 32 + p;
        int cnt = ccnt[wv][p]; if (cnt > LCAND) cnt = LCAND;

        // exact f64 refine + softmax (||x||^2 dropped: common mode in softmax)
        double xa = (double)x[(size_t)n * DIM + lane];
        double xb = (double)x[(size_t)n * DIM + 64 + lane];

        double myd = 1e300; int myk = -1;
        for (int c = 0; c < cnt; ++c) {
            int k = clist[wv][p][c];
            double pr = xa * Cf64[(size_t)k * DIM + lane] + xb * Cf64[(size_t)k * DIM + 64 + lane];
            #pragma unroll
            for (int m = 1; m < 64; m <<= 1) pr += __shfl_xor(pr, m);
            double dist = csqd[k] - 2.0 * pr;
            if (lane == c) { myd = dist; myk = k; }
        }
        double md = myd;
        #pragma unroll
        for (int m = 1; m < 64; m <<= 1) md = fmin(md, __shfl_xor(md, m));
        double zm = -md / BETA;
        double arg = (myk >= 0) ? (-myd / BETA - zm) : -1e300;
        double e = (myk >= 0) ? exp(arg) : 0.0;
        double esum = e;
        #pragma unroll
        for (int m = 1; m < 64; m <<= 1) esum += __shfl_xor(esum, m);

        if (myk >= 0 && arg >= ACUT) {
            double wgt = e / esum;             // once, on the candidate lane only
            size_t base = (size_t)myk * NSUB + sub;
            unsigned pos = atomicAdd(&cursor[base * CSTRIDE], 1u);
            if (pos < SUBCAP) {
                entries_n[base * SUBCAP + pos] = (unsigned)n;
                entries_w[base * SUBCAP + pos] = wgt;
            }
        }
    }
}

// ---------------- k_reduce: gather per-center entries, partial f64 sums ----------------
// 2048 blocks = 4 partials per center (2 sub-buckets each); 128 threads (one per dim)
__global__ void k_reduce(const float* __restrict__ x, const unsigned* __restrict__ cursor,
                         const unsigned* __restrict__ entries_n,
                         const double* __restrict__ entries_w,
                         double* __restrict__ num, double* __restrict__ den) {
    int b = blockIdx.x;
    int k = b >> 2, part = b & 3;
    int d = threadIdx.x;

    double a0 = 0.0, a1 = 0.0, a2 = 0.0, a3 = 0.0, ws = 0.0;
    #pragma unroll
    for (int s = 0; s < 2; ++s) {
        int sub = part * 2 + s;
        size_t base = (size_t)k * NSUB + sub;
        unsigned len = cursor[base * CSTRIDE]; if (len > SUBCAP) len = SUBCAP;
        const unsigned* en = entries_n + base * SUBCAP;
        const double*   ew = entries_w + base * SUBCAP;
        unsigned e = 0;
        for (; e + 4 <= len; e += 4) {
            unsigned n0 = en[e], n1 = en[e + 1], n2 = en[e + 2], n3 = en[e + 3];
            double w0 = ew[e], w1 = ew[e + 1], w2 = ew[e + 2], w3 = ew[e + 3];
            float f0 = x[(size_t)n0 * DIM + d];
            float f1 = x[(size_t)n1 * DIM + d];
            float f2 = x[(size_t)n2 * DIM + d];
            float f3 = x[(size_t)n3 * DIM + d];
            a0 += w0 * (double)f0; a1 += w1 * (double)f1;
            a2 += w2 * (double)f2; a3 += w3 * (double)f3;
            ws += ((w0 + w1) + (w2 + w3));
        }
        for (; e < len; ++e) {
            unsigned n0 = en[e]; double w0 = ew[e];
            a0 += w0 * (double)x[(size_t)n0 * DIM + d];
            ws += w0;
        }
    }
    double acc = (a0 + a1) + (a2 + a3);
    atomicAdd(&num[(size_t)k * DIM + d], acc);
    if (d == 0) atomicAdd(&den[k], ws);
}

// ---------------- k_update: centers = num/(den+EPS); refresh; zero num/den/cursors ----------------
__global__ void k_update(double* __restrict__ num, double* __restrict__ den,
                         double* __restrict__ Cf64, unsigned short* __restrict__ Cfrag,
                         double* __restrict__ csqd, float* __restrict__ csqf,
                         unsigned* __restrict__ cursor, float* __restrict__ out, int last) {
    int k = blockIdx.x, d = threadIdx.x;       // 512 blocks x 128 threads
    double nv = num[(size_t)k * DIM + d];
    double dv = den[k] + EPS;
    double c = nv / dv;
    Cf64[(size_t)k * DIM + d] = c;
    num[(size_t)k * DIM + d] = 0.0;
    if (d < NSUB) cursor[((size_t)k * NSUB + d) * CSTRIDE] = 0u;
    if (last) out[k * DIM + d] = (float)c;
    int ct = k >> 5, kb = d >> 4, j = d & 15;
    int lane = (k & 31) + 32 * (j >> 3);
    Cfrag[(((size_t)ct * 8 + kb) * 64 + lane) * 8 + (j & 7)] = f2bf((float)c);
    double p = c * c;
    #pragma unroll
    for (int m = 1; m < 64; m <<= 1) p += __shfl_xor(p, m);
    __shared__ double ps[2];
    if ((d & 63) == 0) ps[d >> 6] = p;
    __syncthreads();
    if (d == 0) {
        double s = ps[0] + ps[1];
        csqd[k] = s; csqf[k] = (float)s;
        den[k] = 0.0;
    }
}

extern "C" void kernel_launch(void* const* d_in, const int* in_sizes, int n_in,
                              void* d_out, int out_size, void* d_ws, size_t ws_size,
                              hipStream_t stream) {
    const float* x   = (const float*)d_in[0];
    const float* cin = (const float*)d_in[1];
    float* out = (float*)d_out;

    char* w = (char*)d_ws;
    size_t off = 0;
    auto alloc = [&](size_t bytes) -> void* {
        void* p = w + off;
        off = (off + bytes + 255) & ~(size_t)255;
        return p;
    };
    double*         Cf64   = (double*)alloc((size_t)KC * DIM * 8);          // 512 KB
    unsigned short* Cfrag  = (unsigned short*)alloc((size_t)KC * DIM * 2);  // 128 KB
    double*         csqd   = (double*)alloc((size_t)KC * 8);
    float*          csqf   = (float*)alloc((size_t)KC * 4);
    double*         num    = (double*)alloc((size_t)KC * DIM * 8);          // 512 KB
    double*         den    = (double*)alloc((size_t)KC * 8);
    unsigned*       cursor = (unsigned*)alloc((size_t)KC * NSUB * CSTRIDE * 4);   // 256 KB
    unsigned*       entries_n = (unsigned*)alloc((size_t)KC * NSUB * SUBCAP * 4); // 8.4 MB
    double*         entries_w = (double*)alloc((size_t)KC * NSUB * SUBCAP * 8);   // 16.8 MB
    short8*         Xf     = (short8*)alloc((size_t)N_PTS * DIM * 2);       // 51.2 MB
    (void)ws_size; (void)in_sizes; (void)n_in; (void)out_size;

    hipLaunchKernelGGL(k_init, dim3(KC), dim3(DIM), 0, stream,
                       cin, Cf64, Cfrag, csqd, csqf, num, den, cursor);
    hipLaunchKernelGGL(k_packx, dim3(NTILE), dim3(256), 0, stream, x, Xf);

    for (int it = 0; it < NITER; ++it) {
        hipLaunchKernelGGL(k_dense, dim3((NTILE + 3) / 4), dim3(256), 0, stream,
                           x, Xf, (const short8*)Cfrag, csqf, Cf64, csqd,
                           cursor, entries_n, entries_w);
        hipLaunchKernelGGL(k_reduce, dim3(KC * 4), dim3(DIM), 0, stream,
                           x, cursor, entries_n, entries_w, num, den);
        hipLaunchKernelGGL(k_update, dim3(KC), dim3(DIM), 0, stream,
                           num, den, Cf64, Cfrag, csqd, csqf, cursor, out,
                           (it == NITER - 1) ? 1 : 0);
    }
}

// Round 14
// 490.952 us; speedup vs baseline: 1.2112x; 1.2112x over previous
//
#include <hip/hip_runtime.h>

#define N_PTS 200000
#define KC    512
#define DIM   128
#define NITER 3
#define EPS   1e-10
#define BETA  1e-3
#define PWIN  0.35f     // bf16-pruner window: f64 arg>=-32 band (0.032) + >10sigma bf16 slack
#define ACUT  -32.0     // weights below e^-32 shift centers ~1e-12 -> negligible
#define LCAND 16
#define NSUB  8         // sub-buckets per center (atomic line-contention fix, R11)
#define SUBCAP 512      // per-sub bucket capacity (total 4096/center)
#define CSTRIDE 16      // cursor padded to 64 B: one cache line per sub-cursor
#define NTILE (N_PTS / 32)   // 6250 point-tiles

typedef __attribute__((ext_vector_type(8)))  short short8;   // 8 bf16 (4 VGPR) MFMA A/B frag
typedef __attribute__((ext_vector_type(16))) float f32x16;   // 32x32 MFMA accumulator

__device__ inline unsigned short f2bf(float f) {             // f32 -> bf16 RNE
    unsigned u = __float_as_uint(f);
    unsigned r = u + 0x7FFFu + ((u >> 16) & 1u);
    return (unsigned short)(r >> 16);
}

// A/B fragment layout for mfma_f32_32x32x16_bf16: entity row/col = lane&31,
// k = (lane>>5)*8 + i, i=0..7. Packed flat: [(tile*8 + kb)*64 + lane] as short8.

// ---------------- k_packx: X -> bf16 A-fragments (once; x is iteration-invariant) ----------------
__global__ void k_packx(const float* __restrict__ x, short8* __restrict__ Xf) {
    int pt = blockIdx.x;                       // 6250 point-tiles of 32
    int tid = threadIdx.x;                     // 256
    int lane = tid & 63, g = tid >> 6;
    int row = pt * 32 + (lane & 31);
    int koff = (lane >> 5) * 8;
    #pragma unroll
    for (int kk = 0; kk < 2; ++kk) {
        int kb = g * 2 + kk;
        short8 v;
        #pragma unroll
        for (int i = 0; i < 8; ++i)
            ((unsigned short*)&v)[i] = f2bf(x[(size_t)row * DIM + kb * 16 + koff + i]);
        Xf[((size_t)pt * 8 + kb) * 64 + lane] = v;
    }
}

// ---------------- k_init: Cf64, C-fragments, csq, zero num/den/cursors ----------------
__global__ void k_init(const float* __restrict__ cin, double* __restrict__ Cf64,
                       unsigned short* __restrict__ Cfrag, double* __restrict__ csqd,
                       float* __restrict__ csqf, double* __restrict__ num,
                       double* __restrict__ den, unsigned* __restrict__ cursor) {
    int k = blockIdx.x, d = threadIdx.x;       // 512 blocks x 128 threads
    float v = cin[k * DIM + d];
    double c = (double)v;
    Cf64[(size_t)k * DIM + d] = c;
    num[(size_t)k * DIM + d] = 0.0;
    if (d < NSUB) cursor[((size_t)k * NSUB + d) * CSTRIDE] = 0u;
    int ct = k >> 5, kb = d >> 4, j = d & 15;
    int lane = (k & 31) + 32 * (j >> 3);
    Cfrag[(((size_t)ct * 8 + kb) * 64 + lane) * 8 + (j & 7)] = f2bf(v);
    double p = c * c;
    #pragma unroll
    for (int m = 1; m < 64; m <<= 1) p += __shfl_xor(p, m);
    __shared__ double ps[2];
    if ((d & 63) == 0) ps[d >> 6] = p;
    __syncthreads();
    if (d == 0) {
        double s = ps[0] + ps[1];
        csqd[k] = s; csqf[k] = (float)s;
        den[k] = 0.0;
    }
}

// ---------------- k_dense: 8-wave tile; 1-pass MFMA prune + full-min + f64 refine ----------------
// 512 threads = 8 waves; ONE 32-point tile per block; wave wv covers col-tiles
// {wv*2, wv*2+1} (64 centers). Half the per-wave chain of R11, 2x the waves:
// R10-R13 showed wave count (not ILP) is the lever on this latency-bound kernel.
__launch_bounds__(512, 4)
__global__ void k_dense(const float* __restrict__ x, const short8* __restrict__ Xf,
                        const short8* __restrict__ Cfrag, const float* __restrict__ csqf,
                        const double* __restrict__ Cf64, const double* __restrict__ csqd,
                        unsigned* __restrict__ cursor,
                        unsigned* __restrict__ entries_n, double* __restrict__ entries_w) {
    __shared__ float          rowmin_w[8][32];
    __shared__ float          rowmin_s[32];
    __shared__ int            ccnt[32];
    __shared__ unsigned short clist[32][LCAND];
    __shared__ int            wl[32];
    __shared__ int            wlcnt;

    const int tid = threadIdx.x;
    const int wv = tid >> 6, lane = tid & 63;
    const int blk = blockIdx.x;                // one tile per block; 6250 blocks
    const int sub = blk & (NSUB - 1);
    const int h = lane >> 5;

    // A-fragments: this tile's 32 points (all 8 waves load the same -> L1 hits)
    short8 a[8];
    #pragma unroll
    for (int kb = 0; kb < 8; ++kb)
        a[kb] = Xf[((size_t)blk * 8 + kb) * 64 + lane];

    // pruner: dd[t][r] = csq - 2*(x.c), 2 col-tiles per wave, held in registers
    float dd[2][16];
    #pragma unroll
    for (int t = 0; t < 2; ++t) {
        int ct = wv * 2 + t;
        f32x16 acc;
        #pragma unroll
        for (int r = 0; r < 16; ++r) acc[r] = 0.0f;
        #pragma unroll
        for (int kb = 0; kb < 8; ++kb) {
            short8 b = Cfrag[((size_t)ct * 8 + kb) * 64 + lane];
            acc = __builtin_amdgcn_mfma_f32_32x32x16_bf16(a[kb], b, acc, 0, 0, 0);
        }
        float cq = csqf[ct * 32 + (lane & 31)];
        #pragma unroll
        for (int r = 0; r < 16; ++r) dd[t][r] = cq - 2.0f * acc[r];
    }

    // per-row min over this wave's 64 cols (C/D layout: col=lane&31, row=(r&3)+8*(r>>2)+4*(lane>>5))
    float mt[16];
    #pragma unroll
    for (int r = 0; r < 16; ++r) {
        float m = fminf(dd[0][r], dd[1][r]);
        #pragma unroll
        for (int s = 16; s >= 1; s >>= 1) m = fminf(m, __shfl_xor(m, s));
        mt[r] = m;
    }
    if ((lane & 31) == 0) {
        #pragma unroll
        for (int r = 0; r < 16; ++r)
            rowmin_w[wv][(r & 3) + 8 * (r >> 2) + 4 * h] = mt[r];
    }
    __syncthreads();
    if (tid < 32) {
        float m = rowmin_w[0][tid];
        #pragma unroll
        for (int w8 = 1; w8 < 8; ++w8) m = fminf(m, rowmin_w[w8][tid]);
        rowmin_s[tid] = m;
        ccnt[tid] = 0;
    }
    if (tid == 0) wlcnt = 0;
    __syncthreads();

    // candidate collection (full global min known BEFORE any collection)
    #pragma unroll
    for (int t = 0; t < 2; ++t) {
        int ct = wv * 2 + t;
        #pragma unroll
        for (int r = 0; r < 16; ++r) {
            int row = (r & 3) + 8 * (r >> 2) + 4 * h;
            if (dd[t][r] - rowmin_s[row] < PWIN) {
                int idx = atomicAdd(&ccnt[row], 1);
                if (idx < LCAND)
                    clist[row][idx] = (unsigned short)(ct * 32 + (lane & 31));
            }
        }
    }
    __syncthreads();

    // cnt==1 fast path, PARALLEL: lanes 0..3 of each wave handle 4 points.
    // Sole candidate IS the argmin; all others sit >= ~e^-250 below in f64
    // => weight is bit-exactly 1.0. No dot, no softmax, no x read.
    if (lane < 4) {
        int p = wv * 4 + lane;
        if (ccnt[p] == 1) {
            int k = clist[p][0];
            size_t base = (size_t)k * NSUB + sub;
            unsigned pos = atomicAdd(&cursor[base * CSTRIDE], 1u);
            if (pos < SUBCAP) {
                entries_n[base * SUBCAP + pos] = (unsigned)(blk * 32 + p);
                entries_w[base * SUBCAP + pos] = 1.0;
            }
        }
    }
    // worklist of cnt>=2 points; all 8 waves strip-mine it (load balance)
    if (tid < 32 && ccnt[tid] > 1) {
        int i = atomicAdd(&wlcnt, 1);
        wl[i] = tid;
    }
    __syncthreads();

    int nwl = wlcnt;
    for (int i = wv; i < nwl; i += 8) {
        int p = wl[i];
        int n = blk * 32 + p;
        int cnt = ccnt[p]; if (cnt > LCAND) cnt = LCAND;

        // exact f64 refine + softmax (||x||^2 dropped: common mode in softmax)
        double xa = (double)x[(size_t)n * DIM + lane];
        double xb = (double)x[(size_t)n * DIM + 64 + lane];

        double myd = 1e300; int myk = -1;
        for (int c = 0; c < cnt; ++c) {
            int k = clist[p][c];
            double pr = xa * Cf64[(size_t)k * DIM + lane] + xb * Cf64[(size_t)k * DIM + 64 + lane];
            #pragma unroll
            for (int m = 1; m < 64; m <<= 1) pr += __shfl_xor(pr, m);
            double dist = csqd[k] - 2.0 * pr;
            if (lane == c) { myd = dist; myk = k; }
        }
        double md = myd;
        #pragma unroll
        for (int m = 1; m < 64; m <<= 1) md = fmin(md, __shfl_xor(md, m));
        double zm = -md / BETA;
        double arg = (myk >= 0) ? (-myd / BETA - zm) : -1e300;
        double e = (myk >= 0) ? exp(arg) : 0.0;
        double esum = e;
        #pragma unroll
        for (int m = 1; m < 64; m <<= 1) esum += __shfl_xor(esum, m);

        if (myk >= 0 && arg >= ACUT) {
            double wgt = e / esum;             // once, on the candidate lane only
            size_t base = (size_t)myk * NSUB + sub;
            unsigned pos = atomicAdd(&cursor[base * CSTRIDE], 1u);
            if (pos < SUBCAP) {
                entries_n[base * SUBCAP + pos] = (unsigned)n;
                entries_w[base * SUBCAP + pos] = wgt;
            }
        }
    }
}

// ---------------- k_reduce: gather per-center entries, partial f64 sums ----------------
// 2048 blocks = 4 partials per center (2 sub-buckets each); 128 threads (one per dim)
__global__ void k_reduce(const float* __restrict__ x, const unsigned* __restrict__ cursor,
                         const unsigned* __restrict__ entries_n,
                         const double* __restrict__ entries_w,
                         double* __restrict__ num, double* __restrict__ den) {
    int b = blockIdx.x;
    int k = b >> 2, part = b & 3;
    int d = threadIdx.x;

    double a0 = 0.0, a1 = 0.0, a2 = 0.0, a3 = 0.0, ws = 0.0;
    #pragma unroll
    for (int s = 0; s < 2; ++s) {
        int sub = part * 2 + s;
        size_t base = (size_t)k * NSUB + sub;
        unsigned len = cursor[base * CSTRIDE]; if (len > SUBCAP) len = SUBCAP;
        const unsigned* en = entries_n + base * SUBCAP;
        const double*   ew = entries_w + base * SUBCAP;
        unsigned e = 0;
        for (; e + 4 <= len; e += 4) {
            unsigned n0 = en[e], n1 = en[e + 1], n2 = en[e + 2], n3 = en[e + 3];
            double w0 = ew[e], w1 = ew[e + 1], w2 = ew[e + 2], w3 = ew[e + 3];
            float f0 = x[(size_t)n0 * DIM + d];
            float f1 = x[(size_t)n1 * DIM + d];
            float f2 = x[(size_t)n2 * DIM + d];
            float f3 = x[(size_t)n3 * DIM + d];
            a0 += w0 * (double)f0; a1 += w1 * (double)f1;
            a2 += w2 * (double)f2; a3 += w3 * (double)f3;
            ws += ((w0 + w1) + (w2 + w3));
        }
        for (; e < len; ++e) {
            unsigned n0 = en[e]; double w0 = ew[e];
            a0 += w0 * (double)x[(size_t)n0 * DIM + d];
            ws += w0;
        }
    }
    double acc = (a0 + a1) + (a2 + a3);
    atomicAdd(&num[(size_t)k * DIM + d], acc);
    if (d == 0) atomicAdd(&den[k], ws);
}

// ---------------- k_update: centers = num/(den+EPS); refresh; zero num/den/cursors ----------------
__global__ void k_update(double* __restrict__ num, double* __restrict__ den,
                         double* __restrict__ Cf64, unsigned short* __restrict__ Cfrag,
                         double* __restrict__ csqd, float* __restrict__ csqf,
                         unsigned* __restrict__ cursor, float* __restrict__ out, int last) {
    int k = blockIdx.x, d = threadIdx.x;       // 512 blocks x 128 threads
    double nv = num[(size_t)k * DIM + d];
    double dv = den[k] + EPS;
    double c = nv / dv;
    Cf64[(size_t)k * DIM + d] = c;
    num[(size_t)k * DIM + d] = 0.0;
    if (d < NSUB) cursor[((size_t)k * NSUB + d) * CSTRIDE] = 0u;
    if (last) out[k * DIM + d] = (float)c;
    int ct = k >> 5, kb = d >> 4, j = d & 15;
    int lane = (k & 31) + 32 * (j >> 3);
    Cfrag[(((size_t)ct * 8 + kb) * 64 + lane) * 8 + (j & 7)] = f2bf((float)c);
    double p = c * c;
    #pragma unroll
    for (int m = 1; m < 64; m <<= 1) p += __shfl_xor(p, m);
    __shared__ double ps[2];
    if ((d & 63) == 0) ps[d >> 6] = p;
    __syncthreads();
    if (d == 0) {
        double s = ps[0] + ps[1];
        csqd[k] = s; csqf[k] = (float)s;
        den[k] = 0.0;
    }
}

extern "C" void kernel_launch(void* const* d_in, const int* in_sizes, int n_in,
                              void* d_out, int out_size, void* d_ws, size_t ws_size,
                              hipStream_t stream) {
    const float* x   = (const float*)d_in[0];
    const float* cin = (const float*)d_in[1];
    float* out = (float*)d_out;

    char* w = (char*)d_ws;
    size_t off = 0;
    auto alloc = [&](size_t bytes) -> void* {
        void* p = w + off;
        off = (off + bytes + 255) & ~(size_t)255;
        return p;
    };
    double*         Cf64   = (double*)alloc((size_t)KC * DIM * 8);          // 512 KB
    unsigned short* Cfrag  = (unsigned short*)alloc((size_t)KC * DIM * 2);  // 128 KB
    double*         csqd   = (double*)alloc((size_t)KC * 8);
    float*          csqf   = (float*)alloc((size_t)KC * 4);
    double*         num    = (double*)alloc((size_t)KC * DIM * 8);          // 512 KB
    double*         den    = (double*)alloc((size_t)KC * 8);
    unsigned*       cursor = (unsigned*)alloc((size_t)KC * NSUB * CSTRIDE * 4);   // 256 KB
    unsigned*       entries_n = (unsigned*)alloc((size_t)KC * NSUB * SUBCAP * 4); // 8.4 MB
    double*         entries_w = (double*)alloc((size_t)KC * NSUB * SUBCAP * 8);   // 16.8 MB
    short8*         Xf     = (short8*)alloc((size_t)N_PTS * DIM * 2);       // 51.2 MB
    (void)ws_size; (void)in_sizes; (void)n_in; (void)out_size;

    hipLaunchKernelGGL(k_init, dim3(KC), dim3(DIM), 0, stream,
                       cin, Cf64, Cfrag, csqd, csqf, num, den, cursor);
    hipLaunchKernelGGL(k_packx, dim3(NTILE), dim3(256), 0, stream, x, Xf);

    for (int it = 0; it < NITER; ++it) {
        hipLaunchKernelGGL(k_dense, dim3(NTILE), dim3(512), 0, stream,
                           x, Xf, (const short8*)Cfrag, csqf, Cf64, csqd,
                           cursor, entries_n, entries_w);
        hipLaunchKernelGGL(k_reduce, dim3(KC * 4), dim3(DIM), 0, stream,
                           x, cursor, entries_n, entries_w, num, den);
        hipLaunchKernelGGL(k_update, dim3(KC), dim3(DIM), 0, stream,
                           num, den, Cf64, Cfrag, csqd, csqf, cursor, out,
                           (it == NITER - 1) ? 1 : 0);
    }
}